// Round 9
// baseline (6249.020 us; speedup 1.0000x reference)
//
#include <hip/hip_runtime.h>
#include <stdint.h>
#include <math.h>

#define B_   64
#define TS_  256
#define TD_  64
#define H_   512
#define E_   512
#define V_   32000
#define G3_  1536

// barrier dword offsets in bars[]
#define ENC_G 0
#define ENC_T 128
#define ENC_F 160
#define DH_G  192
#define DH_T  320
#define DH_F  352
#define DP_G  384
#define DP_T  512
#define DP_F  544

typedef unsigned short u16;
typedef __attribute__((ext_vector_type(8))) short  short8v;
typedef __attribute__((ext_vector_type(4))) float  float4v;

__device__ __forceinline__ u16 f2bf(float x) {
  union { float f; unsigned u; } v; v.f = x;
  unsigned r = v.u + 0x7FFFu + ((v.u >> 16) & 1u);
  return (u16)(r >> 16);
}
__device__ __forceinline__ float bf2f(u16 h) {
  union { unsigned u; float f; } v; v.u = ((unsigned)h) << 16; return v.f;
}
__device__ __forceinline__ float sigm(float x) { return 1.f / (1.f + expf(-x)); }

__device__ __forceinline__ float4v mfma16(short8v a, short8v b, float4v c) {
  return __builtin_amdgcn_mfma_f32_16x16x32_bf16(a, b, c, 0, 0, 0);
}

// ---- LLC-coherent primitives (bypass L1/L2) ----
__device__ __forceinline__ void st2_sc(u16* p, u16 v) {
  unsigned vv = v;
  asm volatile("global_store_short %0, %1, off sc0 sc1" :: "v"(p), "v"(vv) : "memory");
}
__device__ __forceinline__ void st4_sc(float* p, float v) {
  asm volatile("global_store_dword %0, %1, off sc0 sc1" :: "v"(p), "v"(v) : "memory");
}
__device__ __forceinline__ void st4u_sc(unsigned* p, unsigned v) {
  asm volatile("global_store_dword %0, %1, off sc0 sc1" :: "v"(p), "v"(v) : "memory");
}
__device__ __forceinline__ void st16f_sc(float* p, float4v v) {
  asm volatile("global_store_dwordx4 %0, %1, off sc0 sc1" :: "v"(p), "v"(v) : "memory");
}
__device__ __forceinline__ short8v ld16_sc(const u16* p) {
  short8v r;
  asm volatile("global_load_dwordx4 %0, %1, off sc0 sc1\ns_waitcnt vmcnt(0)"
               : "=v"(r) : "v"(p) : "memory");
  return r;
}
__device__ __forceinline__ unsigned ld_cnt(const unsigned* p) {
  unsigned r;
  asm volatile("global_load_dword %0, %1, off sc0 sc1\ns_waitcnt vmcnt(0)"
               : "=v"(r) : "v"(p) : "memory");
  return r;
}

// hierarchical arrival: group counter (32 blocks) -> top counter -> epoch flag
__device__ __forceinline__ void block_arrive(unsigned* bars, int goff, int grp,
                                             int toff, int foff, unsigned ngrp, unsigned step) {
  asm volatile("s_waitcnt vmcnt(0)" ::: "memory");
  __syncthreads();
  if (threadIdx.x == 0) {
    unsigned o = __hip_atomic_fetch_add(bars + goff + (grp << 5), 1u,
                                        __ATOMIC_RELAXED, __HIP_MEMORY_SCOPE_AGENT);
    if (o == step * 32u - 1u) {
      unsigned o2 = __hip_atomic_fetch_add(bars + toff, 1u,
                                           __ATOMIC_RELAXED, __HIP_MEMORY_SCOPE_AGENT);
      if (o2 == step * ngrp - 1u)
        st4u_sc(bars + foff, step);
    }
  }
}
// spin on epoch flag (plain sc loads, own cache line, no RMW contention)
__device__ __forceinline__ void wait_flag(unsigned* bars, int foff, unsigned step, unsigned* sdead) {
  __syncthreads();
  if (threadIdx.x == 0 && !*sdead) {
    unsigned spins = 0;
    while (ld_cnt(bars + foff) < step) {
      __builtin_amdgcn_s_sleep(4);
      if (++spins > (1u << 23)) { *sdead = 1u; break; }  // valve: never hang harness
    }
  }
  __syncthreads();
}

// ---------------- embedding gather + bf16 hi/lo split ----------------
__global__ __launch_bounds__(256) void k_embed(const int* __restrict__ seq,
    const float* __restrict__ emb, u16* __restrict__ hi, u16* __restrict__ lo, int total8) {
  int idx = blockIdx.x * 256 + threadIdx.x;
  if (idx >= total8) return;
  int row = idx >> 6;
  int c8  = (idx & 63) << 3;
  const float* src = emb + (size_t)seq[row] * E_ + c8;
  short8v hv, lv;
  #pragma unroll
  for (int i = 0; i < 8; ++i) {
    float x = src[i];
    u16 hb2 = f2bf(x);
    hv[i] = (short)hb2;
    lv[i] = (short)f2bf(x - bf2f(hb2));
  }
  *(short8v*)(hi + (size_t)idx * 8) = hv;
  *(short8v*)(lo + (size_t)idx * 8) = lv;
}

// ---------------- f32 [K][N] -> bf16 [N][K] transpose-convert (optional lo) ----------------
template<bool LO>
__global__ __launch_bounds__(256) void k_transp(const float* __restrict__ src, int ld,
    u16* __restrict__ dh, u16* __restrict__ dl, int K, int N) {
  __shared__ float t[64][65];
  int n0 = blockIdx.x << 6, k0 = blockIdx.y << 6;
  int c = threadIdx.x & 63, r0 = threadIdx.x >> 6;
  #pragma unroll
  for (int i = 0; i < 16; ++i) {
    int r = r0 + (i << 2);
    t[r][c] = src[(size_t)(k0 + r) * ld + n0 + c];
  }
  __syncthreads();
  #pragma unroll
  for (int i = 0; i < 16; ++i) {
    int rr = r0 + (i << 2);
    float v = t[c][rr];
    u16 hb2 = f2bf(v);
    size_t o = (size_t)(n0 + rr) * K + k0 + c;
    dh[o] = hb2;
    if (LO) dl[o] = f2bf(v - bf2f(hb2));
  }
}

// ---------------- bf16 MFMA GEMM: C[M,N] = A[M,K] @ B^T (+bias) ----------------
__device__ __forceinline__ int swzA(int row, int q) {
  return (row << 5) + ((q ^ ((row >> 1) & 3)) << 3);
}

template<bool SPLIT, bool BF32N, bool BIAS, bool OBF>
__global__ __launch_bounds__(256, 2) void k_gemm(
    const u16* __restrict__ Ah, const u16* __restrict__ Al,
    const u16* __restrict__ Bh, const u16* __restrict__ Bl,
    const float* __restrict__ Bf,
    float* __restrict__ C, u16* __restrict__ Cb, const float* __restrict__ bias,
    int M, int N, int K)
{
  __shared__ u16 sA[4096], sB[4096];
  __shared__ u16 sA2[SPLIT ? 4096 : 16], sB2[SPLIT ? 4096 : 16];
  const int tid = threadIdx.x;
  const int ln = tid & 63, wv = tid >> 6;
  const int wr = wv >> 1, wc = wv & 1;
  const int m0 = blockIdx.y << 7, n0 = blockIdx.x << 7;
  const int lm = ln & 15, lq = ln >> 4;
  const float4v zf = {0.f, 0.f, 0.f, 0.f};

  float4v acc[4][4];
  #pragma unroll
  for (int i = 0; i < 4; ++i)
    #pragma unroll
    for (int j = 0; j < 4; ++j) acc[i][j] = zf;

  for (int kt = 0; kt < K; kt += 32) {
    #pragma unroll
    for (int s = 0; s < 2; ++s) {
      int id = tid + (s << 8);
      int row = id >> 2, q = id & 3;
      size_t goA = (size_t)(m0 + row) * K + kt + (q << 3);
      int lo = swzA(row, q);
      *(short8v*)&sA[lo] = *(const short8v*)(Ah + goA);
      if constexpr (!BF32N) {
        size_t goB = (size_t)(n0 + row) * K + kt + (q << 3);
        *(short8v*)&sB[lo] = *(const short8v*)(Bh + goB);
        if constexpr (SPLIT) {
          *(short8v*)&sA2[lo] = *(const short8v*)(Al + goA);
          *(short8v*)&sB2[lo] = *(const short8v*)(Bl + goB);
        }
      }
    }
    if constexpr (BF32N) {
      int k = tid >> 3, nc = (tid & 7) << 4;
      const float* bp = Bf + (size_t)(kt + k) * N + n0 + nc;
      int q = k >> 3, e = k & 7;
      #pragma unroll
      for (int j = 0; j < 16; ++j)
        sB[swzA(nc + j, q) + e] = f2bf(bp[j]);
    }
    __syncthreads();
    short8v af[4], bfr[4];
    #pragma unroll
    for (int i = 0; i < 4; ++i) {
      af[i]  = *(const short8v*)&sA[swzA((wr << 6) + (i << 4) + lm, lq)];
      bfr[i] = *(const short8v*)&sB[swzA((wc << 6) + (i << 4) + lm, lq)];
    }
    if constexpr (SPLIT) {
      short8v af2[4], bfr2[4];
      #pragma unroll
      for (int i = 0; i < 4; ++i) {
        af2[i]  = *(const short8v*)&sA2[swzA((wr << 6) + (i << 4) + lm, lq)];
        bfr2[i] = *(const short8v*)&sB2[swzA((wc << 6) + (i << 4) + lm, lq)];
      }
      #pragma unroll
      for (int mi = 0; mi < 4; ++mi)
        #pragma unroll
        for (int ni = 0; ni < 4; ++ni) {
          acc[mi][ni] = mfma16(af[mi],  bfr[ni],  acc[mi][ni]);
          acc[mi][ni] = mfma16(af2[mi], bfr[ni],  acc[mi][ni]);
          acc[mi][ni] = mfma16(af[mi],  bfr2[ni], acc[mi][ni]);
        }
    } else {
      #pragma unroll
      for (int mi = 0; mi < 4; ++mi)
        #pragma unroll
        for (int ni = 0; ni < 4; ++ni)
          acc[mi][ni] = mfma16(af[mi], bfr[ni], acc[mi][ni]);
    }
    __syncthreads();
  }
  #pragma unroll
  for (int mi = 0; mi < 4; ++mi)
    #pragma unroll
    for (int ni = 0; ni < 4; ++ni) {
      int col = n0 + (wc << 6) + (ni << 4) + lm;
      float bv = BIAS ? bias[col] : 0.f;
      #pragma unroll
      for (int i = 0; i < 4; ++i) {
        int row = m0 + (wr << 6) + (mi << 4) + (lq << 2) + i;
        float v = acc[mi][ni][i] + bv;
        size_t o = (size_t)row * N + col;
        if (OBF) Cb[o] = f2bf(v);
        else     C[o] = v;
      }
    }
}

// ---------------- persistent encoder (r4-verbatim) ----------------
__global__ __launch_bounds__(256, 1) void k_encoder(
    const float* __restrict__ gx, const float* __restrict__ Wh,
    u16* hb, u16* __restrict__ ehs, unsigned* bars)
{
  __shared__ char smem[32768];
  __shared__ float rec_s[3][16][16];
  __shared__ unsigned sdead;
  const int tid = threadIdx.x, bid = blockIdx.x;
  const int ln = tid & 63, wv = tid >> 6;
  const int lm = ln & 15, lq = ln >> 4, lq8 = lq << 3;
  const int set = bid >> 5, colblk = bid & 31, grp = bid >> 5;
  const int s16 = set << 4;
  const int jx = tid & 15, bl = tid >> 4;
  const int jg = (colblk << 4) + jx;
  const int b  = s16 + bl;
  if (tid == 0) sdead = 0;

  short8v wfh[16], wfl[16];
  if (wv < 3) {
    const int col = (wv << 9) + (colblk << 4) + lm;
    #pragma unroll
    for (int kt = 0; kt < 16; ++kt) {
      short8v a, b2;
      #pragma unroll
      for (int i = 0; i < 8; ++i) {
        float w = Wh[(size_t)((kt << 5) + lq8 + i) * G3_ + col];
        u16 hb2 = f2bf(w);
        a[i]  = (short)hb2;
        b2[i] = (short)f2bf(w - bf2f(hb2));
      }
      wfh[kt] = a; wfl[kt] = b2;
    }
  }
  const float4v zf = {0.f, 0.f, 0.f, 0.f};
  for (int t = 0; t < TS_; ++t) {
    if (t == 0) {
      short8v zz = {0,0,0,0,0,0,0,0};
      #pragma unroll
      for (int i = 0; i < 8; ++i)
        *(short8v*)(smem + ((tid + (i << 8)) << 4)) = zz;
      __syncthreads();
    } else {
      wait_flag(bars, ENC_F, (unsigned)t, &sdead);
      const u16* cur = hb + ((t & 1) ? 65536 : 0);
      short8v v[8];
      #pragma unroll
      for (int i = 0; i < 8; ++i) {
        int c = tid + (i << 8);
        int half = c >> 10, rem = c & 1023;
        int r = rem >> 6, col16 = rem & 63;
        const u16* p = cur + (half << 15) + ((s16 + r) << 9) + (col16 << 3);
        asm volatile("global_load_dwordx4 %0, %1, off sc0 sc1" : "=v"(v[i]) : "v"(p));
      }
      asm volatile("s_waitcnt vmcnt(0)" ::: "memory");
      __builtin_amdgcn_sched_barrier(0);
      #pragma unroll
      for (int i = 0; i < 8; ++i) {
        int c = tid + (i << 8);
        int half = c >> 10, rem = c & 1023;
        int r = rem >> 6, col16 = rem & 63;
        *(short8v*)(smem + ((half << 14) | (r << 10) | ((col16 << 4) ^ ((r & 7) << 4)))) = v[i];
      }
      __syncthreads();
    }
    float gzv, grv, ghv;
    {
      size_t rg = (size_t)((b << 8) + t) * G3_ + jg;
      gzv = gx[rg]; grv = gx[rg + 512]; ghv = gx[rg + 1024];
    }
    int hoff = (bl << 10) | ((jg << 1) ^ ((bl & 7) << 4));
    float hold = bf2f(*(const u16*)(smem + hoff)) + bf2f(*(const u16*)(smem + 16384 + hoff));
    if (wv < 3) {
      float4v acc = zf;
      #pragma unroll
      for (int kt = 0; kt < 16; ++kt) {
        int aoff = (lm << 10) | (((kt << 6) + (lq << 4)) ^ ((lm & 7) << 4));
        short8v ah = *(const short8v*)(smem + aoff);
        short8v al = *(const short8v*)(smem + 16384 + aoff);
        acc = mfma16(ah, wfh[kt], acc);
        acc = mfma16(al, wfh[kt], acc);
        acc = mfma16(ah, wfl[kt], acc);
      }
      #pragma unroll
      for (int i = 0; i < 4; ++i) rec_s[wv][(lq << 2) + i][lm] = acc[i];
    }
    __syncthreads();
    {
      float z  = sigm(gzv + rec_s[0][bl][jx]);
      float r  = sigm(grv + rec_s[1][bl][jx]);
      float hh = tanhf(ghv + r * rec_s[2][bl][jx]);
      float hnew = z * hold + (1.f - z) * hh;
      u16 nh = f2bf(hnew);
      u16* hnx = hb + ((t & 1) ? 0 : 65536);
      st2_sc(hnx + (b << 9) + jg, nh);
      st2_sc(hnx + 32768 + (b << 9) + jg, f2bf(hnew - bf2f(nh)));
      ehs[(size_t)((b << 8) + t) * 512 + jg] = nh;
    }
    if (t < TS_ - 1)
      block_arrive(bars, ENC_G, grp, ENC_T, ENC_F, 4u, (unsigned)(t + 1));
  }
}

// ---------------- persistent decoder: 128 rec + 128 attn ----------------
// r4 structure + e2 math; NEW: in-block q (scores from ehs.q) + vectorized weighted-sum.
__global__ __launch_bounds__(256, 1) void k_decoder(
    const float* __restrict__ gxd, const float* __restrict__ Wh,
    const u16* __restrict__ wattT, const u16* __restrict__ ehs, const u16* __restrict__ e2,
    u16* hb, float* pnum, float* pden, u16* __restrict__ outs, unsigned* bars)
{
  __shared__ char smem[32768];
  __shared__ float rec_s[3][16][16];
  __shared__ float hsumf[512];
  __shared__ float qpart[2][512];
  __shared__ float q_lds[512];
  __shared__ float ps[128][2];
  __shared__ float es[128];
  __shared__ float wsum[2];
  __shared__ unsigned sdead;
  const int tid = threadIdx.x, bid = blockIdx.x;
  const int ln = tid & 63, wv = tid >> 6;
  const int lm = ln & 15, lq = ln >> 4, lq8 = lq << 3;
  const bool isrec = (bid < 128);
  const int set = bid >> 5, colblk = bid & 31;
  const int s16 = set << 4;
  const int jx = tid & 15, bl = tid >> 4;
  const int jg = (colblk << 4) + jx;
  const int b  = s16 + bl;
  const int ab = bid - 128, batt = ab >> 1, cset = ab & 1;
  if (tid == 0) sdead = 0;
  __syncthreads();

  short8v wfh[16], wfl[16];
  if (isrec && wv < 3) {
    const int col = (wv << 9) + (colblk << 4) + lm;
    #pragma unroll
    for (int kt = 0; kt < 16; ++kt) {
      short8v a, b2;
      #pragma unroll
      for (int i = 0; i < 8; ++i) {
        float w = Wh[(size_t)((kt << 5) + lq8 + i) * G3_ + col];
        u16 hb2 = f2bf(w);
        a[i]  = (short)hb2;
        b2[i] = (short)f2bf(w - bf2f(hb2));
      }
      wfh[kt] = a; wfl[kt] = b2;
    }
  }
  const float4v zf = {0.f, 0.f, 0.f, 0.f};
  for (int t = 0; t < TD_; ++t) {
    const u16* cur = hb + ((t & 1) ? 65536 : 0);
    if (isrec) {
      if (t) wait_flag(bars, DH_F, (unsigned)t, &sdead);
      {  // stage h(t) slice -> LDS
        short8v v[8];
        #pragma unroll
        for (int i = 0; i < 8; ++i) {
          int c = tid + (i << 8);
          int half = c >> 10, rem = c & 1023;
          int r = rem >> 6, col16 = rem & 63;
          const u16* p = cur + (half << 15) + ((s16 + r) << 9) + (col16 << 3);
          asm volatile("global_load_dwordx4 %0, %1, off sc0 sc1" : "=v"(v[i]) : "v"(p));
        }
        asm volatile("s_waitcnt vmcnt(0)" ::: "memory");
        __builtin_amdgcn_sched_barrier(0);
        #pragma unroll
        for (int i = 0; i < 8; ++i) {
          int c = tid + (i << 8);
          int half = c >> 10, rem = c & 1023;
          int r = rem >> 6, col16 = rem & 63;
          *(short8v*)(smem + ((half << 14) | (r << 10) | ((col16 << 4) ^ ((r & 7) << 4)))) = v[i];
        }
        __syncthreads();
      }
      float gzv, grv, ghv;
      {
        size_t rg = (size_t)((b << 6) + t) * G3_ + jg;
        gzv = gxd[rg]; grv = gxd[rg + 512]; ghv = gxd[rg + 1024];
      }
      int hoff = (bl << 10) | ((jg << 1) ^ ((bl & 7) << 4));
      float hold = bf2f(*(const u16*)(smem + hoff)) + bf2f(*(const u16*)(smem + 16384 + hoff));
      if (wv < 3) {
        float4v acc = zf;
        #pragma unroll
        for (int kt = 0; kt < 16; ++kt) {
          int aoff = (lm << 10) | (((kt << 6) + (lq << 4)) ^ ((lm & 7) << 4));
          short8v ah = *(const short8v*)(smem + aoff);
          short8v al = *(const short8v*)(smem + 16384 + aoff);
          acc = mfma16(ah, wfh[kt], acc);
          acc = mfma16(al, wfh[kt], acc);
          acc = mfma16(ah, wfl[kt], acc);
        }
        #pragma unroll
        for (int i = 0; i < 4; ++i) rec_s[wv][(lq << 2) + i][lm] = acc[i];
      }
      __syncthreads();
      wait_flag(bars, DP_F, (unsigned)(t + 1), &sdead);
      {  // batched sc loads of attention partials (r4 math)
        const float* p0 = pnum + (size_t)(b << 1) * G3_ + jg;
        const float* p1 = p0 + G3_;
        float pv0, pv1, pv2, pv3, pv4, pv5, d0, d1;
        asm volatile("global_load_dword %0, %1, off sc0 sc1" : "=v"(pv0) : "v"(p0));
        asm volatile("global_load_dword %0, %1, off sc0 sc1" : "=v"(pv1) : "v"(p0 + 512));
        asm volatile("global_load_dword %0, %1, off sc0 sc1" : "=v"(pv2) : "v"(p0 + 1024));
        asm volatile("global_load_dword %0, %1, off sc0 sc1" : "=v"(pv3) : "v"(p1));
        asm volatile("global_load_dword %0, %1, off sc0 sc1" : "=v"(pv4) : "v"(p1 + 512));
        asm volatile("global_load_dword %0, %1, off sc0 sc1" : "=v"(pv5) : "v"(p1 + 1024));
        asm volatile("global_load_dword %0, %1, off sc0 sc1" : "=v"(d0) : "v"(pden + (b << 1)));
        asm volatile("global_load_dword %0, %1, off sc0 sc1" : "=v"(d1) : "v"(pden + (b << 1) + 1));
        asm volatile("s_waitcnt vmcnt(0)" ::: "memory");
        __builtin_amdgcn_sched_barrier(0);
        float inv = 1.f / (d0 + d1);
        float z  = sigm(gzv + (pv0 + pv3) * inv + rec_s[0][bl][jx]);
        float r  = sigm(grv + (pv1 + pv4) * inv + rec_s[1][bl][jx]);
        float hh = tanhf(ghv + (pv2 + pv5) * inv + r * rec_s[2][bl][jx]);
        float hnew = z * hold + (1.f - z) * hh;
        u16 nh = f2bf(hnew);
        outs[(size_t)((b << 6) + t) * 512 + jg] = nh;
        if (t < TD_ - 1) {
          u16* hnx = hb + ((t & 1) ? 0 : 65536);
          st2_sc(hnx + (b << 9) + jg, nh);
          st2_sc(hnx + 32768 + (b << 9) + jg, f2bf(hnew - bf2f(nh)));
        }
      }
      if (t < TD_ - 1)
        block_arrive(bars, DH_G, set, DH_T, DH_F, 4u, (unsigned)(t + 1));
    } else {
      if (t) wait_flag(bars, DH_F, (unsigned)t, &sdead);
      if (tid < 64) {  // stage h[batt] (hi+lo summed f32)
        short8v hv = ld16_sc(cur + (batt << 9) + (tid << 3));
        short8v lv = ld16_sc(cur + 32768 + (batt << 9) + (tid << 3));
        #pragma unroll
        for (int j = 0; j < 8; ++j)
          hsumf[(tid << 3) + j] = bf2f((u16)hv[j]) + bf2f((u16)lv[j]);
      }
      __syncthreads();
      { // q = hsum @ W_att : thread -> 4 c' cols, 2-way k-split; wattT L2-hot
        int cq = (tid & 127) << 2;
        int kh = tid >> 7;
        const u16* w0 = wattT + (size_t)cq * 512 + (kh << 8);
        float a0 = 0.f, a1 = 0.f, a2 = 0.f, a3 = 0.f;
        #pragma unroll 4
        for (int kc = 0; kc < 32; ++kc) {
          short8v r0 = *(const short8v*)(w0 + (kc << 3));
          short8v r1 = *(const short8v*)(w0 + 512 + (kc << 3));
          short8v r2 = *(const short8v*)(w0 + 1024 + (kc << 3));
          short8v r3 = *(const short8v*)(w0 + 1536 + (kc << 3));
          #pragma unroll
          for (int j = 0; j < 8; ++j) {
            float hv = hsumf[(kh << 8) + (kc << 3) + j];
            a0 += hv * bf2f((u16)r0[j]);
            a1 += hv * bf2f((u16)r1[j]);
            a2 += hv * bf2f((u16)r2[j]);
            a3 += hv * bf2f((u16)r3[j]);
          }
        }
        qpart[kh][cq] = a0; qpart[kh][cq + 1] = a1;
        qpart[kh][cq + 2] = a2; qpart[kh][cq + 3] = a3;
      }
      __syncthreads();
      if (tid < 128) {
        #pragma unroll
        for (int j = 0; j < 4; ++j) {
          int c = (tid << 2) + j;
          q_lds[c] = qpart[0][c] + qpart[1][c];
        }
      }
      __syncthreads();
      { // scores: ehs[t'] . q, 2-way k-split
        int tt = tid >> 1, kq = tid & 1;
        const u16* ep = ehs + (size_t)((batt << 8) + (cset << 7) + tt) * 512 + (kq << 8);
        float s = 0.f;
        #pragma unroll 4
        for (int k8 = 0; k8 < 32; ++k8) {
          short8v ev = *(const short8v*)(ep + (k8 << 3));
          #pragma unroll
          for (int i = 0; i < 8; ++i)
            s += bf2f((u16)ev[i]) * q_lds[(kq << 8) + (k8 << 3) + i];
        }
        ps[tt][kq] = s;
      }
      __syncthreads();
      if (tid < 128) {  // scores are small; exp without max is safe
        float e = expf(ps[tid][0] + ps[tid][1]);
        es[tid] = e;
        #pragma unroll
        for (int off = 32; off; off >>= 1) e += __shfl_down(e, off);
        if ((tid & 63) == 0) wsum[tid >> 6] = e;
      }
      __syncthreads();
      if (tid == 0) st4_sc(&pden[(batt << 1) + cset], wsum[0] + wsum[1]);
      if (tid < 192) { // weighted sums over e2 (1536 cols): 8 contiguous cols/thread, vector loads
        int c0 = tid << 3;
        const u16* base = e2 + (size_t)((batt << 8) + (cset << 7)) * G3_ + c0;
        float a[8] = {0.f,0.f,0.f,0.f,0.f,0.f,0.f,0.f};
        #pragma unroll 4
        for (int tt2 = 0; tt2 < 128; ++tt2) {
          short8v cv = *(const short8v*)(base + (size_t)tt2 * G3_);
          float w = es[tt2];
          #pragma unroll
          for (int j = 0; j < 8; ++j)
            a[j] += w * bf2f((u16)cv[j]);
        }
        float* pn = pnum + (size_t)((batt << 1) + cset) * G3_ + c0;
        float4v v0 = {a[0], a[1], a[2], a[3]};
        float4v v1 = {a[4], a[5], a[6], a[7]};
        st16f_sc(pn, v0);
        st16f_sc(pn + 4, v1);
      }
      block_arrive(bars, DP_G, ab >> 5, DP_T, DP_F, 4u, (unsigned)(t + 1));
    }
  }
}

extern "C" void kernel_launch(void* const* d_in, const int* in_sizes, int n_in,
                              void* d_out, int out_size, void* d_ws, size_t ws_size,
                              hipStream_t stream) {
  const int*   src_seq = (const int*)d_in[0];
  const int*   dec_seq = (const int*)d_in[1];
  const float* emb     = (const float*)d_in[2];
  const float* enc_Wx  = (const float*)d_in[3];
  const float* enc_Wh  = (const float*)d_in[4];
  const float* enc_b   = (const float*)d_in[5];
  const float* dec_Wx  = (const float*)d_in[6];
  const float* dec_Wh  = (const float*)d_in[7];
  const float* dec_b   = (const float*)d_in[8];
  const float* W_att   = (const float*)d_in[9];
  const float* Wd      = (const float*)d_in[10];
  const float* bd      = (const float*)d_in[11];

  // d_out doubles as scratch; final projection reads ONLY ws+inputs.
  char* ob = (char*)d_out;
  float* gx_all  = (float*)(ob + 0);           // [16384][1536] f32
  float* gxd_all = (float*)(ob + 100663296);   // [4096][1536] f32
  u16* srcE_h = (u16*)(ob + 125829120);
  u16* srcE_l = (u16*)(ob + 142606336);
  u16* decE_h = (u16*)(ob + 159383552);
  u16* decE_l = (u16*)(ob + 163577856);
  u16* ehs    = (u16*)(ob + 167772160);        // [64][256][512] bf16
  u16* e2b    = (u16*)(ob + 201326592);        // E~2 bf16 [16384][1536]
  u16* wxT_h  = (u16*)(ob + 251658240);
  u16* wxT_l  = (u16*)(ob + 253231104);
  u16* wdxT_h = (u16*)(ob + 254803968);
  u16* wdxT_l = (u16*)(ob + 256376832);
  u16* wxcT   = (u16*)(ob + 257949696);        // dec_Wx[512:]^T
  u16* wattT  = (u16*)(ob + 259522560);        // W_att^T bf16 [512][512]
  u16* hbuf   = (u16*)(ob + 260046848);        // h dbl-buffer hi/lo

  char* wb = (char*)d_ws;
  u16* outs     = (u16*)(wb + 0);              // [4096][512] bf16
  float* pnum   = (float*)(wb + 4194304);      // [128][1536] f32
  float* pden   = (float*)(wb + 4980736);      // [128]
  unsigned* bars = (unsigned*)(wb + 4981248);  // hierarchical counters + flags
  (void)in_sizes; (void)n_in; (void)out_size; (void)ws_size;

  hipMemsetAsync(bars, 0, 4096, stream);

  k_embed<<<4096, 256, 0, stream>>>(src_seq, emb, srcE_h, srcE_l, B_*TS_*64);
  k_embed<<<1024, 256, 0, stream>>>(dec_seq, emb, decE_h, decE_l, B_*TD_*64);
  k_transp<true ><<<dim3(24, 8), 256, 0, stream>>>(enc_Wx, G3_, wxT_h,  wxT_l,  512, G3_);
  k_transp<true ><<<dim3(24, 8), 256, 0, stream>>>(dec_Wx, G3_, wdxT_h, wdxT_l, 512, G3_);
  k_transp<false><<<dim3(24, 8), 256, 0, stream>>>(dec_Wx + (size_t)512*G3_, G3_, wxcT, nullptr, 512, G3_);
  k_transp<false><<<dim3(8, 8),  256, 0, stream>>>(W_att, 512, wattT, nullptr, 512, 512);

  // gate-feeding input transforms: split-precision 3-term bf16 GEMMs
  k_gemm<true, false, true, false><<<dim3(12, 128), 256, 0, stream>>>(
      srcE_h, srcE_l, wxT_h, wxT_l, nullptr, gx_all, nullptr, enc_b, 16384, G3_, 512);
  k_gemm<true, false, true, false><<<dim3(12, 32), 256, 0, stream>>>(
      decE_h, decE_l, wdxT_h, wdxT_l, nullptr, gxd_all, nullptr, dec_b, 4096, G3_, 512);

  k_encoder<<<128, 256, 0, stream>>>(gx_all, enc_Wh, hbuf, ehs, bars);

  // e2 = ehs @ dec_Wx[512:]^T (bf16) — verified attention-path precompute
  k_gemm<false, false, false, true><<<dim3(12, 128), 256, 0, stream>>>(
      ehs, nullptr, wxcT, nullptr, nullptr, nullptr, e2b, nullptr, 16384, G3_, 512);

  k_decoder<<<256, 256, 0, stream>>>(gxd_all, dec_Wh, wattT, ehs, e2b,
                                     hbuf, pnum, pden, outs, bars);

  // vocab projection: A = outs (ws), B = Wd f32 on-the-fly, writes all of d_out
  k_gemm<false, true, true, false><<<dim3(250, 32), 256, 0, stream>>>(
      outs, nullptr, nullptr, nullptr, Wd, (float*)d_out, nullptr, bd, 4096, V_, 512);
}

// Round 10
// 5635.749 us; speedup vs baseline: 1.1088x; 1.1088x over previous
//
#include <hip/hip_runtime.h>
#include <stdint.h>
#include <math.h>

#define B_   64
#define TS_  256
#define TD_  64
#define H_   512
#define E_   512
#define V_   32000
#define G3_  1536

// barrier dword offsets in bars[]
#define ENC_G 0
#define ENC_T 128
#define ENC_F 160
#define DH_G  192
#define DH_T  320
#define DH_F  352
#define DP_G  384   // 8 groups x 32
#define DP_T  640
#define DP_F  672

typedef unsigned short u16;
typedef __attribute__((ext_vector_type(8))) short  short8v;
typedef __attribute__((ext_vector_type(4))) float  float4v;

__device__ __forceinline__ u16 f2bf(float x) {
  union { float f; unsigned u; } v; v.f = x;
  unsigned r = v.u + 0x7FFFu + ((v.u >> 16) & 1u);
  return (u16)(r >> 16);
}
__device__ __forceinline__ float bf2f(u16 h) {
  union { unsigned u; float f; } v; v.u = ((unsigned)h) << 16; return v.f;
}
__device__ __forceinline__ float sigm(float x) { return 1.f / (1.f + expf(-x)); }

__device__ __forceinline__ float4v mfma16(short8v a, short8v b, float4v c) {
  return __builtin_amdgcn_mfma_f32_16x16x32_bf16(a, b, c, 0, 0, 0);
}

// ---- LLC-coherent primitives (bypass L1/L2) ----
__device__ __forceinline__ void st2_sc(u16* p, u16 v) {
  unsigned vv = v;
  asm volatile("global_store_short %0, %1, off sc0 sc1" :: "v"(p), "v"(vv) : "memory");
}
__device__ __forceinline__ void st4_sc(float* p, float v) {
  asm volatile("global_store_dword %0, %1, off sc0 sc1" :: "v"(p), "v"(v) : "memory");
}
__device__ __forceinline__ void st4u_sc(unsigned* p, unsigned v) {
  asm volatile("global_store_dword %0, %1, off sc0 sc1" :: "v"(p), "v"(v) : "memory");
}
__device__ __forceinline__ void st16f_sc(float* p, float4v v) {
  asm volatile("global_store_dwordx4 %0, %1, off sc0 sc1" :: "v"(p), "v"(v) : "memory");
}
__device__ __forceinline__ unsigned ld_cnt(const unsigned* p) {
  unsigned r;
  asm volatile("global_load_dword %0, %1, off sc0 sc1\ns_waitcnt vmcnt(0)"
               : "=v"(r) : "v"(p) : "memory");
  return r;
}

// hierarchical arrival: group counter (32 blocks) -> top counter -> epoch flag
__device__ __forceinline__ void block_arrive(unsigned* bars, int goff, int grp,
                                             int toff, int foff, unsigned ngrp, unsigned step) {
  asm volatile("s_waitcnt vmcnt(0)" ::: "memory");
  __syncthreads();
  if (threadIdx.x == 0) {
    unsigned o = __hip_atomic_fetch_add(bars + goff + (grp << 5), 1u,
                                        __ATOMIC_RELAXED, __HIP_MEMORY_SCOPE_AGENT);
    if (o == step * 32u - 1u) {
      unsigned o2 = __hip_atomic_fetch_add(bars + toff, 1u,
                                           __ATOMIC_RELAXED, __HIP_MEMORY_SCOPE_AGENT);
      if (o2 == step * ngrp - 1u)
        st4u_sc(bars + foff, step);
    }
  }
}
// spin on epoch flag (plain sc loads, own cache line, no RMW contention)
__device__ __forceinline__ void wait_flag(unsigned* bars, int foff, unsigned step, unsigned* sdead) {
  __syncthreads();
  if (threadIdx.x == 0 && !*sdead) {
    unsigned spins = 0;
    while (ld_cnt(bars + foff) < step) {
      __builtin_amdgcn_s_sleep(4);
      if (++spins > (1u << 23)) { *sdead = 1u; break; }  // valve: never hang harness
    }
  }
  __syncthreads();
}

// ---------------- embedding gather + bf16 hi/lo split ----------------
__global__ __launch_bounds__(256) void k_embed(const int* __restrict__ seq,
    const float* __restrict__ emb, u16* __restrict__ hi, u16* __restrict__ lo, int total8) {
  int idx = blockIdx.x * 256 + threadIdx.x;
  if (idx >= total8) return;
  int row = idx >> 6;
  int c8  = (idx & 63) << 3;
  const float* src = emb + (size_t)seq[row] * E_ + c8;
  short8v hv, lv;
  #pragma unroll
  for (int i = 0; i < 8; ++i) {
    float x = src[i];
    u16 hb2 = f2bf(x);
    hv[i] = (short)hb2;
    lv[i] = (short)f2bf(x - bf2f(hb2));
  }
  *(short8v*)(hi + (size_t)idx * 8) = hv;
  *(short8v*)(lo + (size_t)idx * 8) = lv;
}

// ---------------- f32 [K][N] -> bf16 [N][K] transpose-convert (optional lo) ----------------
template<bool LO>
__global__ __launch_bounds__(256) void k_transp(const float* __restrict__ src, int ld,
    u16* __restrict__ dh, u16* __restrict__ dl, int K, int N) {
  __shared__ float t[64][65];
  int n0 = blockIdx.x << 6, k0 = blockIdx.y << 6;
  int c = threadIdx.x & 63, r0 = threadIdx.x >> 6;
  #pragma unroll
  for (int i = 0; i < 16; ++i) {
    int r = r0 + (i << 2);
    t[r][c] = src[(size_t)(k0 + r) * ld + n0 + c];
  }
  __syncthreads();
  #pragma unroll
  for (int i = 0; i < 16; ++i) {
    int rr = r0 + (i << 2);
    float v = t[c][rr];
    u16 hb2 = f2bf(v);
    size_t o = (size_t)(n0 + rr) * K + k0 + c;
    dh[o] = hb2;
    if (LO) dl[o] = f2bf(v - bf2f(hb2));
  }
}

__global__ __launch_bounds__(256) void k_cvt(const float* __restrict__ s, u16* __restrict__ d, int n) {
  int i = blockIdx.x * 256 + threadIdx.x;
  if (i < n) d[i] = f2bf(s[i]);
}

// ---------------- bf16 MFMA GEMM: C[M,N] = A[M,K] @ B^T (+bias) ----------------
__device__ __forceinline__ int swzA(int row, int q) {
  return (row << 5) + ((q ^ ((row >> 1) & 3)) << 3);
}

template<bool SPLIT, bool BF32N, bool BIAS, bool OBF>
__global__ __launch_bounds__(256, 2) void k_gemm(
    const u16* __restrict__ Ah, const u16* __restrict__ Al,
    const u16* __restrict__ Bh, const u16* __restrict__ Bl,
    const float* __restrict__ Bf,
    float* __restrict__ C, u16* __restrict__ Cb, const float* __restrict__ bias,
    int M, int N, int K)
{
  __shared__ u16 sA[4096], sB[4096];
  __shared__ u16 sA2[SPLIT ? 4096 : 16], sB2[SPLIT ? 4096 : 16];
  const int tid = threadIdx.x;
  const int ln = tid & 63, wv = tid >> 6;
  const int wr = wv >> 1, wc = wv & 1;
  const int m0 = blockIdx.y << 7, n0 = blockIdx.x << 7;
  const int lm = ln & 15, lq = ln >> 4;
  const float4v zf = {0.f, 0.f, 0.f, 0.f};

  float4v acc[4][4];
  #pragma unroll
  for (int i = 0; i < 4; ++i)
    #pragma unroll
    for (int j = 0; j < 4; ++j) acc[i][j] = zf;

  for (int kt = 0; kt < K; kt += 32) {
    #pragma unroll
    for (int s = 0; s < 2; ++s) {
      int id = tid + (s << 8);
      int row = id >> 2, q = id & 3;
      size_t goA = (size_t)(m0 + row) * K + kt + (q << 3);
      int lo = swzA(row, q);
      *(short8v*)&sA[lo] = *(const short8v*)(Ah + goA);
      if constexpr (!BF32N) {
        size_t goB = (size_t)(n0 + row) * K + kt + (q << 3);
        *(short8v*)&sB[lo] = *(const short8v*)(Bh + goB);
        if constexpr (SPLIT) {
          *(short8v*)&sA2[lo] = *(const short8v*)(Al + goA);
          *(short8v*)&sB2[lo] = *(const short8v*)(Bl + goB);
        }
      }
    }
    if constexpr (BF32N) {
      int k = tid >> 3, nc = (tid & 7) << 4;
      const float* bp = Bf + (size_t)(kt + k) * N + n0 + nc;
      int q = k >> 3, e = k & 7;
      #pragma unroll
      for (int j = 0; j < 16; ++j)
        sB[swzA(nc + j, q) + e] = f2bf(bp[j]);
    }
    __syncthreads();
    short8v af[4], bfr[4];
    #pragma unroll
    for (int i = 0; i < 4; ++i) {
      af[i]  = *(const short8v*)&sA[swzA((wr << 6) + (i << 4) + lm, lq)];
      bfr[i] = *(const short8v*)&sB[swzA((wc << 6) + (i << 4) + lm, lq)];
    }
    if constexpr (SPLIT) {
      short8v af2[4], bfr2[4];
      #pragma unroll
      for (int i = 0; i < 4; ++i) {
        af2[i]  = *(const short8v*)&sA2[swzA((wr << 6) + (i << 4) + lm, lq)];
        bfr2[i] = *(const short8v*)&sB2[swzA((wc << 6) + (i << 4) + lm, lq)];
      }
      #pragma unroll
      for (int mi = 0; mi < 4; ++mi)
        #pragma unroll
        for (int ni = 0; ni < 4; ++ni) {
          acc[mi][ni] = mfma16(af[mi],  bfr[ni],  acc[mi][ni]);
          acc[mi][ni] = mfma16(af2[mi], bfr[ni],  acc[mi][ni]);
          acc[mi][ni] = mfma16(af[mi],  bfr2[ni], acc[mi][ni]);
        }
    } else {
      #pragma unroll
      for (int mi = 0; mi < 4; ++mi)
        #pragma unroll
        for (int ni = 0; ni < 4; ++ni)
          acc[mi][ni] = mfma16(af[mi], bfr[ni], acc[mi][ni]);
    }
    __syncthreads();
  }
  #pragma unroll
  for (int mi = 0; mi < 4; ++mi)
    #pragma unroll
    for (int ni = 0; ni < 4; ++ni) {
      int col = n0 + (wc << 6) + (ni << 4) + lm;
      float bv = BIAS ? bias[col] : 0.f;
      #pragma unroll
      for (int i = 0; i < 4; ++i) {
        int row = m0 + (wr << 6) + (mi << 4) + (lq << 2) + i;
        float v = acc[mi][ni][i] + bv;
        size_t o = (size_t)row * N + col;
        if (OBF) Cb[o] = f2bf(v);
        else     C[o] = v;
      }
    }
}

// ---------------- persistent encoder (verified, unchanged) ----------------
__global__ __launch_bounds__(256, 1) void k_encoder(
    const float* __restrict__ gx, const float* __restrict__ Wh,
    u16* hb, u16* __restrict__ ehs, unsigned* bars)
{
  __shared__ char smem[32768];
  __shared__ float rec_s[3][16][16];
  __shared__ unsigned sdead;
  const int tid = threadIdx.x, bid = blockIdx.x;
  const int ln = tid & 63, wv = tid >> 6;
  const int lm = ln & 15, lq = ln >> 4, lq8 = lq << 3;
  const int set = bid >> 5, colblk = bid & 31, grp = bid >> 5;
  const int s16 = set << 4;
  const int jx = tid & 15, bl = tid >> 4;
  const int jg = (colblk << 4) + jx;
  const int b  = s16 + bl;
  if (tid == 0) sdead = 0;

  short8v wfh[16], wfl[16];
  if (wv < 3) {
    const int col = (wv << 9) + (colblk << 4) + lm;
    #pragma unroll
    for (int kt = 0; kt < 16; ++kt) {
      short8v a, b2;
      #pragma unroll
      for (int i = 0; i < 8; ++i) {
        float w = Wh[(size_t)((kt << 5) + lq8 + i) * G3_ + col];
        u16 hb2 = f2bf(w);
        a[i]  = (short)hb2;
        b2[i] = (short)f2bf(w - bf2f(hb2));
      }
      wfh[kt] = a; wfl[kt] = b2;
    }
  }
  const float4v zf = {0.f, 0.f, 0.f, 0.f};
  for (int t = 0; t < TS_; ++t) {
    if (t == 0) {
      short8v zz = {0,0,0,0,0,0,0,0};
      #pragma unroll
      for (int i = 0; i < 8; ++i)
        *(short8v*)(smem + ((tid + (i << 8)) << 4)) = zz;
      __syncthreads();
    } else {
      wait_flag(bars, ENC_F, (unsigned)t, &sdead);
      const u16* cur = hb + ((t & 1) ? 65536 : 0);
      short8v v[8];
      #pragma unroll
      for (int i = 0; i < 8; ++i) {
        int c = tid + (i << 8);
        int half = c >> 10, rem = c & 1023;
        int r = rem >> 6, col16 = rem & 63;
        const u16* p = cur + (half << 15) + ((s16 + r) << 9) + (col16 << 3);
        asm volatile("global_load_dwordx4 %0, %1, off sc0 sc1" : "=v"(v[i]) : "v"(p));
      }
      asm volatile("s_waitcnt vmcnt(0)" ::: "memory");
      __builtin_amdgcn_sched_barrier(0);
      #pragma unroll
      for (int i = 0; i < 8; ++i) {
        int c = tid + (i << 8);
        int half = c >> 10, rem = c & 1023;
        int r = rem >> 6, col16 = rem & 63;
        *(short8v*)(smem + ((half << 14) | (r << 10) | ((col16 << 4) ^ ((r & 7) << 4)))) = v[i];
      }
      __syncthreads();
    }
    float gzv, grv, ghv;
    {
      size_t rg = (size_t)((b << 8) + t) * G3_ + jg;
      gzv = gx[rg]; grv = gx[rg + 512]; ghv = gx[rg + 1024];
    }
    int hoff = (bl << 10) | ((jg << 1) ^ ((bl & 7) << 4));
    float hold = bf2f(*(const u16*)(smem + hoff)) + bf2f(*(const u16*)(smem + 16384 + hoff));
    if (wv < 3) {
      float4v acc = zf;
      #pragma unroll
      for (int kt = 0; kt < 16; ++kt) {
        int aoff = (lm << 10) | (((kt << 6) + (lq << 4)) ^ ((lm & 7) << 4));
        short8v ah = *(const short8v*)(smem + aoff);
        short8v al = *(const short8v*)(smem + 16384 + aoff);
        acc = mfma16(ah, wfh[kt], acc);
        acc = mfma16(al, wfh[kt], acc);
        acc = mfma16(ah, wfl[kt], acc);
      }
      #pragma unroll
      for (int i = 0; i < 4; ++i) rec_s[wv][(lq << 2) + i][lm] = acc[i];
    }
    __syncthreads();
    {
      float z  = sigm(gzv + rec_s[0][bl][jx]);
      float r  = sigm(grv + rec_s[1][bl][jx]);
      float hh = tanhf(ghv + r * rec_s[2][bl][jx]);
      float hnew = z * hold + (1.f - z) * hh;
      u16 nh = f2bf(hnew);
      u16* hnx = hb + ((t & 1) ? 0 : 65536);
      st2_sc(hnx + (b << 9) + jg, nh);
      st2_sc(hnx + 32768 + (b << 9) + jg, f2bf(hnew - bf2f(nh)));
      ehs[(size_t)((b << 8) + t) * 512 + jg] = nh;
    }
    if (t < TS_ - 1)
      block_arrive(bars, ENC_G, grp, ENC_T, ENC_F, 4u, (unsigned)(t + 1));
  }
}

// ---------------- persistent decoder: merged roles, 256 blocks ----------------
// every block: attn quarter (batt=bid>>2, cset=bid&3, 64 t'-rows), e2 math (r2-verified),
// coalesced in-block q (r9-verified route). blocks <128 additionally run the rec role.
__global__ __launch_bounds__(256, 1) void k_decoder(
    const float* __restrict__ gxd, const float* __restrict__ Wh,
    const u16* __restrict__ wattB, const u16* __restrict__ ehs, const u16* __restrict__ e2,
    u16* hb, float* pnum, float* pden, u16* __restrict__ outs, unsigned* bars)
{
  __shared__ char smem[32768];
  __shared__ float rec_s[3][16][16];
  __shared__ float hsumf[512];
  __shared__ float qpart[4][512];
  __shared__ float q_lds[512];
  __shared__ float ps[64][4];
  __shared__ float es[64];
  __shared__ unsigned sdead;
  const int tid = threadIdx.x, bid = blockIdx.x;
  const int ln = tid & 63, wv = tid >> 6;
  const int lm = ln & 15, lq = ln >> 4, lq8 = lq << 3;
  const bool isrec = (bid < 128);
  const int set = bid >> 5, colblk = bid & 31;
  const int s16 = set << 4;
  const int jx = tid & 15, bl = tid >> 4;
  const int jg = (colblk << 4) + jx;
  const int b  = s16 + bl;
  const int batt = bid >> 2, cset = bid & 3;
  if (tid == 0) sdead = 0;
  __syncthreads();

  short8v wfh[16], wfl[16];
  if (isrec && wv < 3) {
    const int col = (wv << 9) + (colblk << 4) + lm;
    #pragma unroll
    for (int kt = 0; kt < 16; ++kt) {
      short8v a, b2;
      #pragma unroll
      for (int i = 0; i < 8; ++i) {
        float w = Wh[(size_t)((kt << 5) + lq8 + i) * G3_ + col];
        u16 hb2 = f2bf(w);
        a[i]  = (short)hb2;
        b2[i] = (short)f2bf(w - bf2f(hb2));
      }
      wfh[kt] = a; wfl[kt] = b2;
    }
  }
  const float4v zf = {0.f, 0.f, 0.f, 0.f};
  for (int t = 0; t < TD_; ++t) {
    const u16* cur = hb + ((t & 1) ? 65536 : 0);
    if (t) wait_flag(bars, DH_F, (unsigned)t, &sdead);
    {  // staged loads: rec h-slice (hi/lo) + hsumf, single vmcnt
      short8v v[8], hv, lv;
      if (isrec) {
        #pragma unroll
        for (int i = 0; i < 8; ++i) {
          int c = tid + (i << 8);
          int half = c >> 10, rem = c & 1023;
          int r = rem >> 6, col16 = rem & 63;
          const u16* p = cur + (half << 15) + ((s16 + r) << 9) + (col16 << 3);
          asm volatile("global_load_dwordx4 %0, %1, off sc0 sc1" : "=v"(v[i]) : "v"(p));
        }
      }
      if (tid < 64) {
        const u16* ph = cur + (batt << 9) + (tid << 3);
        asm volatile("global_load_dwordx4 %0, %1, off sc0 sc1" : "=v"(hv) : "v"(ph));
        asm volatile("global_load_dwordx4 %0, %1, off sc0 sc1" : "=v"(lv) : "v"(ph + 32768));
      }
      asm volatile("s_waitcnt vmcnt(0)" ::: "memory");
      __builtin_amdgcn_sched_barrier(0);
      if (isrec) {
        #pragma unroll
        for (int i = 0; i < 8; ++i) {
          int c = tid + (i << 8);
          int half = c >> 10, rem = c & 1023;
          int r = rem >> 6, col16 = rem & 63;
          *(short8v*)(smem + ((half << 14) | (r << 10) | ((col16 << 4) ^ ((r & 7) << 4)))) = v[i];
        }
      }
      if (tid < 64) {
        #pragma unroll
        for (int j = 0; j < 8; ++j)
          hsumf[(tid << 3) + j] = bf2f((u16)hv[j]) + bf2f((u16)lv[j]);
      }
      __syncthreads();
    }
    {  // q = hsum @ W_att, coalesced: wave wv owns k in [wv*128,+128), lane owns 8 cols
      const u16* wp = wattB + ((size_t)(wv << 7) << 9) + (ln << 3);
      float a[8] = {0.f,0.f,0.f,0.f,0.f,0.f,0.f,0.f};
      #pragma unroll 4
      for (int kc = 0; kc < 128; ++kc) {
        short8v wr = *(const short8v*)(wp + ((size_t)kc << 9));
        float hk = hsumf[(wv << 7) + kc];
        #pragma unroll
        for (int j = 0; j < 8; ++j)
          a[j] += hk * bf2f((u16)wr[j]);
      }
      #pragma unroll
      for (int j = 0; j < 8; ++j) qpart[wv][(ln << 3) + j] = a[j];
    }
    __syncthreads();
    if (tid < 128) {
      #pragma unroll
      for (int j = 0; j < 4; ++j) {
        int c = (tid << 2) + j;
        q_lds[c] = ((qpart[0][c] + qpart[1][c]) + qpart[2][c]) + qpart[3][c];
      }
    }
    __syncthreads();
    {  // scores: 64 rows, 4-way k-split (r2-verified pattern)
      int tt = tid >> 2, kq = tid & 3;
      const u16* ep = ehs + (size_t)((batt << 8) + (cset << 6) + tt) * 512 + (kq << 7);
      float s = 0.f;
      #pragma unroll 4
      for (int k8 = 0; k8 < 16; ++k8) {
        short8v ev = *(const short8v*)(ep + (k8 << 3));
        #pragma unroll
        for (int j = 0; j < 8; ++j)
          s += bf2f((u16)ev[j]) * q_lds[(kq << 7) + (k8 << 3) + j];
      }
      ps[tt][kq] = s;
    }
    __syncthreads();
    if (tid < 64) {  // scores small; exp without max is safe
      float e = expf(((ps[tid][0] + ps[tid][1]) + ps[tid][2]) + ps[tid][3]);
      es[tid] = e;
      #pragma unroll
      for (int off = 32; off; off >>= 1) e += __shfl_down(e, off);
      if (tid == 0) st4_sc(&pden[bid], e);
    }
    __syncthreads();
    if (tid < 192) {  // weighted sums over e2 quarter: 8 contiguous cols/thread
      int c0 = tid << 3;
      const u16* base = e2 + (size_t)((batt << 8) + (cset << 6)) * G3_ + c0;
      float a[8] = {0.f,0.f,0.f,0.f,0.f,0.f,0.f,0.f};
      #pragma unroll 4
      for (int r = 0; r < 64; ++r) {
        short8v cv = *(const short8v*)(base + (size_t)r * G3_);
        float w = es[r];
        #pragma unroll
        for (int j = 0; j < 8; ++j)
          a[j] += w * bf2f((u16)cv[j]);
      }
      float* pn = pnum + (size_t)bid * G3_ + c0;
      float4v v0 = {a[0], a[1], a[2], a[3]};
      float4v v1 = {a[4], a[5], a[6], a[7]};
      st16f_sc(pn, v0);
      st16f_sc(pn + 4, v1);
    }
    block_arrive(bars, DP_G, bid >> 5, DP_T, DP_F, 8u, (unsigned)(t + 1));
    if (isrec) {
      float gzv, grv, ghv;
      {
        size_t rg = (size_t)((b << 6) + t) * G3_ + jg;
        gzv = gxd[rg]; grv = gxd[rg + 512]; ghv = gxd[rg + 1024];
      }
      int hoff = (bl << 10) | ((jg << 1) ^ ((bl & 7) << 4));
      float hold = bf2f(*(const u16*)(smem + hoff)) + bf2f(*(const u16*)(smem + 16384 + hoff));
      if (wv < 3) {
        float4v acc = zf;
        #pragma unroll
        for (int kt = 0; kt < 16; ++kt) {
          int aoff = (lm << 10) | (((kt << 6) + (lq << 4)) ^ ((lm & 7) << 4));
          short8v ah = *(const short8v*)(smem + aoff);
          short8v al = *(const short8v*)(smem + 16384 + aoff);
          acc = mfma16(ah, wfh[kt], acc);
          acc = mfma16(al, wfh[kt], acc);
          acc = mfma16(ah, wfl[kt], acc);
        }
        #pragma unroll
        for (int i = 0; i < 4; ++i) rec_s[wv][(lq << 2) + i][lm] = acc[i];
      }
      wait_flag(bars, DP_F, (unsigned)(t + 1), &sdead);
      {  // gates: batched sc loads of 12 pnum + 4 pden (c ascending, r2 order)
        const float* p0 = pnum + (size_t)(b << 2) * G3_ + jg;
        float q0,q1,q2,q3, r0,r1,r2,r3, h0,h1,h2,h3, d0,d1,d2,d3;
        asm volatile("global_load_dword %0, %1, off sc0 sc1" : "=v"(q0) : "v"(p0));
        asm volatile("global_load_dword %0, %1, off sc0 sc1" : "=v"(q1) : "v"(p0 + G3_));
        asm volatile("global_load_dword %0, %1, off sc0 sc1" : "=v"(q2) : "v"(p0 + 2*G3_));
        asm volatile("global_load_dword %0, %1, off sc0 sc1" : "=v"(q3) : "v"(p0 + 3*G3_));
        asm volatile("global_load_dword %0, %1, off sc0 sc1" : "=v"(r0) : "v"(p0 + 512));
        asm volatile("global_load_dword %0, %1, off sc0 sc1" : "=v"(r1) : "v"(p0 + G3_ + 512));
        asm volatile("global_load_dword %0, %1, off sc0 sc1" : "=v"(r2) : "v"(p0 + 2*G3_ + 512));
        asm volatile("global_load_dword %0, %1, off sc0 sc1" : "=v"(r3) : "v"(p0 + 3*G3_ + 512));
        asm volatile("global_load_dword %0, %1, off sc0 sc1" : "=v"(h0) : "v"(p0 + 1024));
        asm volatile("global_load_dword %0, %1, off sc0 sc1" : "=v"(h1) : "v"(p0 + G3_ + 1024));
        asm volatile("global_load_dword %0, %1, off sc0 sc1" : "=v"(h2) : "v"(p0 + 2*G3_ + 1024));
        asm volatile("global_load_dword %0, %1, off sc0 sc1" : "=v"(h3) : "v"(p0 + 3*G3_ + 1024));
        asm volatile("global_load_dword %0, %1, off sc0 sc1" : "=v"(d0) : "v"(pden + (b << 2)));
        asm volatile("global_load_dword %0, %1, off sc0 sc1" : "=v"(d1) : "v"(pden + (b << 2) + 1));
        asm volatile("global_load_dword %0, %1, off sc0 sc1" : "=v"(d2) : "v"(pden + (b << 2) + 2));
        asm volatile("global_load_dword %0, %1, off sc0 sc1" : "=v"(d3) : "v"(pden + (b << 2) + 3));
        asm volatile("s_waitcnt vmcnt(0)" ::: "memory");
        __builtin_amdgcn_sched_barrier(0);
        float inv = 1.f / (((d0 + d1) + d2) + d3);
        float pz  = ((q0 + q1) + q2) + q3;
        float pr  = ((r0 + r1) + r2) + r3;
        float phh = ((h0 + h1) + h2) + h3;
        float z  = sigm(gzv + pz * inv + rec_s[0][bl][jx]);
        float rr = sigm(grv + pr * inv + rec_s[1][bl][jx]);
        float hh = tanhf(ghv + phh * inv + rr * rec_s[2][bl][jx]);
        float hnew = z * hold + (1.f - z) * hh;
        u16 nh = f2bf(hnew);
        outs[(size_t)((b << 6) + t) * 512 + jg] = nh;
        if (t < TD_ - 1) {
          u16* hnx = hb + ((t & 1) ? 0 : 65536);
          st2_sc(hnx + (b << 9) + jg, nh);
          st2_sc(hnx + 32768 + (b << 9) + jg, f2bf(hnew - bf2f(nh)));
        }
      }
      if (t < TD_ - 1)
        block_arrive(bars, DH_G, set, DH_T, DH_F, 4u, (unsigned)(t + 1));
    }
  }
}

extern "C" void kernel_launch(void* const* d_in, const int* in_sizes, int n_in,
                              void* d_out, int out_size, void* d_ws, size_t ws_size,
                              hipStream_t stream) {
  const int*   src_seq = (const int*)d_in[0];
  const int*   dec_seq = (const int*)d_in[1];
  const float* emb     = (const float*)d_in[2];
  const float* enc_Wx  = (const float*)d_in[3];
  const float* enc_Wh  = (const float*)d_in[4];
  const float* enc_b   = (const float*)d_in[5];
  const float* dec_Wx  = (const float*)d_in[6];
  const float* dec_Wh  = (const float*)d_in[7];
  const float* dec_b   = (const float*)d_in[8];
  const float* W_att   = (const float*)d_in[9];
  const float* Wd      = (const float*)d_in[10];
  const float* bd      = (const float*)d_in[11];

  // d_out doubles as scratch; final projection reads ONLY ws+inputs.
  char* ob = (char*)d_out;
  float* gx_all  = (float*)(ob + 0);           // [16384][1536] f32
  float* gxd_all = (float*)(ob + 100663296);   // [4096][1536] f32
  u16* srcE_h = (u16*)(ob + 125829120);
  u16* srcE_l = (u16*)(ob + 142606336);
  u16* decE_h = (u16*)(ob + 159383552);
  u16* decE_l = (u16*)(ob + 163577856);
  u16* ehs    = (u16*)(ob + 167772160);        // [64][256][512] bf16
  u16* e2b    = (u16*)(ob + 201326592);        // [16384][1536] bf16
  u16* wxT_h  = (u16*)(ob + 251658240);
  u16* wxT_l  = (u16*)(ob + 253231104);
  u16* wdxT_h = (u16*)(ob + 254803968);
  u16* wdxT_l = (u16*)(ob + 256376832);
  u16* wxcT   = (u16*)(ob + 257949696);        // dec_Wx[512:]^T
  u16* wattB  = (u16*)(ob + 259522560);        // W_att bf16 [k][c'] (no transpose)
  u16* hbuf   = (u16*)(ob + 260046848);        // h dbl-buffer hi/lo
  float* pnum = (float*)(ob + 264000000);      // [256][1536] f32 quarter partials
  float* pden = (float*)(ob + 266000000);      // [256]

  char* wb = (char*)d_ws;
  u16* outs      = (u16*)(wb + 0);             // [4096][512] bf16
  unsigned* bars = (unsigned*)(wb + 4194304);  // hierarchical counters + flags
  (void)in_sizes; (void)n_in; (void)out_size; (void)ws_size;

  hipMemsetAsync(bars, 0, 4096, stream);

  k_embed<<<4096, 256, 0, stream>>>(src_seq, emb, srcE_h, srcE_l, B_*TS_*64);
  k_embed<<<1024, 256, 0, stream>>>(dec_seq, emb, decE_h, decE_l, B_*TD_*64);
  k_transp<true ><<<dim3(24, 8), 256, 0, stream>>>(enc_Wx, G3_, wxT_h,  wxT_l,  512, G3_);
  k_transp<true ><<<dim3(24, 8), 256, 0, stream>>>(dec_Wx, G3_, wdxT_h, wdxT_l, 512, G3_);
  k_transp<false><<<dim3(24, 8), 256, 0, stream>>>(dec_Wx + (size_t)512*G3_, G3_, wxcT, nullptr, 512, G3_);
  k_cvt<<<1024, 256, 0, stream>>>(W_att, wattB, 512*512);

  // gate-feeding input transforms: split-precision 3-term bf16 GEMMs
  k_gemm<true, false, true, false><<<dim3(12, 128), 256, 0, stream>>>(
      srcE_h, srcE_l, wxT_h, wxT_l, nullptr, gx_all, nullptr, enc_b, 16384, G3_, 512);
  k_gemm<true, false, true, false><<<dim3(12, 32), 256, 0, stream>>>(
      decE_h, decE_l, wdxT_h, wdxT_l, nullptr, gxd_all, nullptr, dec_b, 4096, G3_, 512);

  k_encoder<<<128, 256, 0, stream>>>(gx_all, enc_Wh, hbuf, ehs, bars);

  // e2 = ehs @ dec_Wx[512:]^T (bf16) — verified attention-path precompute
  k_gemm<false, false, false, true><<<dim3(12, 128), 256, 0, stream>>>(
      ehs, nullptr, wxcT, nullptr, nullptr, nullptr, e2b, nullptr, 16384, G3_, 512);

  k_decoder<<<256, 256, 0, stream>>>(gxd_all, dec_Wh, wattB, ehs, e2b,
                                     hbuf, pnum, pden, outs, bars);

  // vocab projection: A = outs (ws), B = Wd f32 on-the-fly, writes all of d_out
  k_gemm<false, true, true, false><<<dim3(250, 32), 256, 0, stream>>>(
      outs, nullptr, nullptr, nullptr, Wd, (float*)d_out, nullptr, bd, 4096, V_, 512);
}

// Round 12
// 3567.000 us; speedup vs baseline: 1.7519x; 1.5800x over previous
//
#include <hip/hip_runtime.h>
#include <stdint.h>
#include <math.h>

#define B_   64
#define TS_  256
#define TD_  64
#define H_   512
#define E_   512
#define V_   32000
#define G3_  1536

// barrier dword offsets in bars[]
#define ENC_G 0
#define ENC_T 128
#define ENC_F 160
#define DH_G  192
#define DH_T  320
#define DH_F  352
#define DP_G  384   // 8 groups x 32
#define DP_T  640
#define DP_F  672

typedef unsigned short u16;
typedef __attribute__((ext_vector_type(8))) short  short8v;
typedef __attribute__((ext_vector_type(4))) float  float4v;

__device__ __forceinline__ u16 f2bf(float x) {
  union { float f; unsigned u; } v; v.f = x;
  unsigned r = v.u + 0x7FFFu + ((v.u >> 16) & 1u);
  return (u16)(r >> 16);
}
__device__ __forceinline__ float bf2f(u16 h) {
  union { unsigned u; float f; } v; v.u = ((unsigned)h) << 16; return v.f;
}
__device__ __forceinline__ float sigm(float x) { return 1.f / (1.f + expf(-x)); }

__device__ __forceinline__ float4v mfma16(short8v a, short8v b, float4v c) {
  return __builtin_amdgcn_mfma_f32_16x16x32_bf16(a, b, c, 0, 0, 0);
}

// ---- LLC-coherent primitives (bypass L1/L2) ----
__device__ __forceinline__ void st2_sc(u16* p, u16 v) {
  unsigned vv = v;
  asm volatile("global_store_short %0, %1, off sc0 sc1" :: "v"(p), "v"(vv) : "memory");
}
__device__ __forceinline__ void st4_sc(float* p, float v) {
  asm volatile("global_store_dword %0, %1, off sc0 sc1" :: "v"(p), "v"(v) : "memory");
}
__device__ __forceinline__ void st4u_sc(unsigned* p, unsigned v) {
  asm volatile("global_store_dword %0, %1, off sc0 sc1" :: "v"(p), "v"(v) : "memory");
}
__device__ __forceinline__ void st16f_sc(float* p, float4v v) {
  asm volatile("global_store_dwordx4 %0, %1, off sc0 sc1" :: "v"(p), "v"(v) : "memory");
}
__device__ __forceinline__ short8v ld16_sc(const u16* p) {
  short8v r;
  asm volatile("global_load_dwordx4 %0, %1, off sc0 sc1\ns_waitcnt vmcnt(0)"
               : "=v"(r) : "v"(p) : "memory");
  return r;
}
__device__ __forceinline__ unsigned ld_cnt(const unsigned* p) {
  unsigned r;
  asm volatile("global_load_dword %0, %1, off sc0 sc1\ns_waitcnt vmcnt(0)"
               : "=v"(r) : "v"(p) : "memory");
  return r;
}

// hierarchical arrival: group counter (32 blocks) -> top counter -> epoch flag
__device__ __forceinline__ void block_arrive(unsigned* bars, int goff, int grp,
                                             int toff, int foff, unsigned ngrp, unsigned step) {
  asm volatile("s_waitcnt vmcnt(0)" ::: "memory");
  __syncthreads();
  if (threadIdx.x == 0) {
    unsigned o = __hip_atomic_fetch_add(bars + goff + (grp << 5), 1u,
                                        __ATOMIC_RELAXED, __HIP_MEMORY_SCOPE_AGENT);
    if (o == step * 32u - 1u) {
      unsigned o2 = __hip_atomic_fetch_add(bars + toff, 1u,
                                           __ATOMIC_RELAXED, __HIP_MEMORY_SCOPE_AGENT);
      if (o2 == step * ngrp - 1u)
        st4u_sc(bars + foff, step);
    }
  }
}
// spin on epoch flag (plain sc loads, own cache line, no RMW contention)
__device__ __forceinline__ void wait_flag(unsigned* bars, int foff, unsigned step, unsigned* sdead) {
  __syncthreads();
  if (threadIdx.x == 0 && !*sdead) {
    unsigned spins = 0;
    while (ld_cnt(bars + foff) < step) {
      __builtin_amdgcn_s_sleep(4);
      if (++spins > (1u << 23)) { *sdead = 1u; break; }  // valve: never hang harness
    }
  }
  __syncthreads();
}

// ---------------- embedding gather + bf16 hi/lo split ----------------
__global__ __launch_bounds__(256) void k_embed(const int* __restrict__ seq,
    const float* __restrict__ emb, u16* __restrict__ hi, u16* __restrict__ lo, int total8) {
  int idx = blockIdx.x * 256 + threadIdx.x;
  if (idx >= total8) return;
  int row = idx >> 6;
  int c8  = (idx & 63) << 3;
  const float* src = emb + (size_t)seq[row] * E_ + c8;
  short8v hv, lv;
  #pragma unroll
  for (int i = 0; i < 8; ++i) {
    float x = src[i];
    u16 hb2 = f2bf(x);
    hv[i] = (short)hb2;
    lv[i] = (short)f2bf(x - bf2f(hb2));
  }
  *(short8v*)(hi + (size_t)idx * 8) = hv;
  *(short8v*)(lo + (size_t)idx * 8) = lv;
}

// ---------------- f32 [K][N] -> bf16 [N][K] transpose-convert (optional lo) ----------------
template<bool LO>
__global__ __launch_bounds__(256) void k_transp(const float* __restrict__ src, int ld,
    u16* __restrict__ dh, u16* __restrict__ dl, int K, int N) {
  __shared__ float t[64][65];
  int n0 = blockIdx.x << 6, k0 = blockIdx.y << 6;
  int c = threadIdx.x & 63, r0 = threadIdx.x >> 6;
  #pragma unroll
  for (int i = 0; i < 16; ++i) {
    int r = r0 + (i << 2);
    t[r][c] = src[(size_t)(k0 + r) * ld + n0 + c];
  }
  __syncthreads();
  #pragma unroll
  for (int i = 0; i < 16; ++i) {
    int rr = r0 + (i << 2);
    float v = t[c][rr];
    u16 hb2 = f2bf(v);
    size_t o = (size_t)(n0 + rr) * K + k0 + c;
    dh[o] = hb2;
    if (LO) dl[o] = f2bf(v - bf2f(hb2));
  }
}

__global__ __launch_bounds__(256) void k_cvt(const float* __restrict__ s, u16* __restrict__ d, int n) {
  int i = blockIdx.x * 256 + threadIdx.x;
  if (i < n) d[i] = f2bf(s[i]);
}

// ---------------- bf16 MFMA GEMM: C[M,N] = A[M,K] @ B^T (+bias) ----------------
__device__ __forceinline__ int swzA(int row, int q) {
  return (row << 5) + ((q ^ ((row >> 1) & 3)) << 3);
}

template<bool SPLIT, bool BF32N, bool BIAS, bool OBF>
__global__ __launch_bounds__(256, 2) void k_gemm(
    const u16* __restrict__ Ah, const u16* __restrict__ Al,
    const u16* __restrict__ Bh, const u16* __restrict__ Bl,
    const float* __restrict__ Bf,
    float* __restrict__ C, u16* __restrict__ Cb, const float* __restrict__ bias,
    int M, int N, int K)
{
  __shared__ u16 sA[4096], sB[4096];
  __shared__ u16 sA2[SPLIT ? 4096 : 16], sB2[SPLIT ? 4096 : 16];
  const int tid = threadIdx.x;
  const int ln = tid & 63, wv = tid >> 6;
  const int wr = wv >> 1, wc = wv & 1;
  const int m0 = blockIdx.y << 7, n0 = blockIdx.x << 7;
  const int lm = ln & 15, lq = ln >> 4;
  const float4v zf = {0.f, 0.f, 0.f, 0.f};

  float4v acc[4][4];
  #pragma unroll
  for (int i = 0; i < 4; ++i)
    #pragma unroll
    for (int j = 0; j < 4; ++j) acc[i][j] = zf;

  for (int kt = 0; kt < K; kt += 32) {
    #pragma unroll
    for (int s = 0; s < 2; ++s) {
      int id = tid + (s << 8);
      int row = id >> 2, q = id & 3;
      size_t goA = (size_t)(m0 + row) * K + kt + (q << 3);
      int lo = swzA(row, q);
      *(short8v*)&sA[lo] = *(const short8v*)(Ah + goA);
      if constexpr (!BF32N) {
        size_t goB = (size_t)(n0 + row) * K + kt + (q << 3);
        *(short8v*)&sB[lo] = *(const short8v*)(Bh + goB);
        if constexpr (SPLIT) {
          *(short8v*)&sA2[lo] = *(const short8v*)(Al + goA);
          *(short8v*)&sB2[lo] = *(const short8v*)(Bl + goB);
        }
      }
    }
    if constexpr (BF32N) {
      int k = tid >> 3, nc = (tid & 7) << 4;
      const float* bp = Bf + (size_t)(kt + k) * N + n0 + nc;
      int q = k >> 3, e = k & 7;
      #pragma unroll
      for (int j = 0; j < 16; ++j)
        sB[swzA(nc + j, q) + e] = f2bf(bp[j]);
    }
    __syncthreads();
    short8v af[4], bfr[4];
    #pragma unroll
    for (int i = 0; i < 4; ++i) {
      af[i]  = *(const short8v*)&sA[swzA((wr << 6) + (i << 4) + lm, lq)];
      bfr[i] = *(const short8v*)&sB[swzA((wc << 6) + (i << 4) + lm, lq)];
    }
    if constexpr (SPLIT) {
      short8v af2[4], bfr2[4];
      #pragma unroll
      for (int i = 0; i < 4; ++i) {
        af2[i]  = *(const short8v*)&sA2[swzA((wr << 6) + (i << 4) + lm, lq)];
        bfr2[i] = *(const short8v*)&sB2[swzA((wc << 6) + (i << 4) + lm, lq)];
      }
      #pragma unroll
      for (int mi = 0; mi < 4; ++mi)
        #pragma unroll
        for (int ni = 0; ni < 4; ++ni) {
          acc[mi][ni] = mfma16(af[mi],  bfr[ni],  acc[mi][ni]);
          acc[mi][ni] = mfma16(af2[mi], bfr[ni],  acc[mi][ni]);
          acc[mi][ni] = mfma16(af[mi],  bfr2[ni], acc[mi][ni]);
        }
    } else {
      #pragma unroll
      for (int mi = 0; mi < 4; ++mi)
        #pragma unroll
        for (int ni = 0; ni < 4; ++ni)
          acc[mi][ni] = mfma16(af[mi], bfr[ni], acc[mi][ni]);
    }
    __syncthreads();
  }
  #pragma unroll
  for (int mi = 0; mi < 4; ++mi)
    #pragma unroll
    for (int ni = 0; ni < 4; ++ni) {
      int col = n0 + (wc << 6) + (ni << 4) + lm;
      float bv = BIAS ? bias[col] : 0.f;
      #pragma unroll
      for (int i = 0; i < 4; ++i) {
        int row = m0 + (wr << 6) + (mi << 4) + (lq << 2) + i;
        float v = acc[mi][ni][i] + bv;
        size_t o = (size_t)row * N + col;
        if (OBF) Cb[o] = f2bf(v);
        else     C[o] = v;
      }
    }
}

// ---------------- persistent encoder (verified, unchanged) ----------------
__global__ __launch_bounds__(256, 1) void k_encoder(
    const float* __restrict__ gx, const float* __restrict__ Wh,
    u16* hb, u16* __restrict__ ehs, unsigned* bars)
{
  __shared__ char smem[32768];
  __shared__ float rec_s[3][16][16];
  __shared__ unsigned sdead;
  const int tid = threadIdx.x, bid = blockIdx.x;
  const int ln = tid & 63, wv = tid >> 6;
  const int lm = ln & 15, lq = ln >> 4, lq8 = lq << 3;
  const int set = bid >> 5, colblk = bid & 31, grp = bid >> 5;
  const int s16 = set << 4;
  const int jx = tid & 15, bl = tid >> 4;
  const int jg = (colblk << 4) + jx;
  const int b  = s16 + bl;
  if (tid == 0) sdead = 0;

  short8v wfh[16], wfl[16];
  if (wv < 3) {
    const int col = (wv << 9) + (colblk << 4) + lm;
    #pragma unroll
    for (int kt = 0; kt < 16; ++kt) {
      short8v a, b2;
      #pragma unroll
      for (int i = 0; i < 8; ++i) {
        float w = Wh[(size_t)((kt << 5) + lq8 + i) * G3_ + col];
        u16 hb2 = f2bf(w);
        a[i]  = (short)hb2;
        b2[i] = (short)f2bf(w - bf2f(hb2));
      }
      wfh[kt] = a; wfl[kt] = b2;
    }
  }
  const float4v zf = {0.f, 0.f, 0.f, 0.f};
  for (int t = 0; t < TS_; ++t) {
    if (t == 0) {
      short8v zz = {0,0,0,0,0,0,0,0};
      #pragma unroll
      for (int i = 0; i < 8; ++i)
        *(short8v*)(smem + ((tid + (i << 8)) << 4)) = zz;
      __syncthreads();
    } else {
      wait_flag(bars, ENC_F, (unsigned)t, &sdead);
      const u16* cur = hb + ((t & 1) ? 65536 : 0);
      short8v v[8];
      #pragma unroll
      for (int i = 0; i < 8; ++i) {
        int c = tid + (i << 8);
        int half = c >> 10, rem = c & 1023;
        int r = rem >> 6, col16 = rem & 63;
        const u16* p = cur + (half << 15) + ((s16 + r) << 9) + (col16 << 3);
        asm volatile("global_load_dwordx4 %0, %1, off sc0 sc1" : "=v"(v[i]) : "v"(p));
      }
      asm volatile("s_waitcnt vmcnt(0)" ::: "memory");
      __builtin_amdgcn_sched_barrier(0);
      #pragma unroll
      for (int i = 0; i < 8; ++i) {
        int c = tid + (i << 8);
        int half = c >> 10, rem = c & 1023;
        int r = rem >> 6, col16 = rem & 63;
        *(short8v*)(smem + ((half << 14) | (r << 10) | ((col16 << 4) ^ ((r & 7) << 4)))) = v[i];
      }
      __syncthreads();
    }
    float gzv, grv, ghv;
    {
      size_t rg = (size_t)((b << 8) + t) * G3_ + jg;
      gzv = gx[rg]; grv = gx[rg + 512]; ghv = gx[rg + 1024];
    }
    int hoff = (bl << 10) | ((jg << 1) ^ ((bl & 7) << 4));
    float hold = bf2f(*(const u16*)(smem + hoff)) + bf2f(*(const u16*)(smem + 16384 + hoff));
    if (wv < 3) {
      float4v acc = zf;
      #pragma unroll
      for (int kt = 0; kt < 16; ++kt) {
        int aoff = (lm << 10) | (((kt << 6) + (lq << 4)) ^ ((lm & 7) << 4));
        short8v ah = *(const short8v*)(smem + aoff);
        short8v al = *(const short8v*)(smem + 16384 + aoff);
        acc = mfma16(ah, wfh[kt], acc);
        acc = mfma16(al, wfh[kt], acc);
        acc = mfma16(ah, wfl[kt], acc);
      }
      #pragma unroll
      for (int i = 0; i < 4; ++i) rec_s[wv][(lq << 2) + i][lm] = acc[i];
    }
    __syncthreads();
    {
      float z  = sigm(gzv + rec_s[0][bl][jx]);
      float r  = sigm(grv + rec_s[1][bl][jx]);
      float hh = tanhf(ghv + r * rec_s[2][bl][jx]);
      float hnew = z * hold + (1.f - z) * hh;
      u16 nh = f2bf(hnew);
      u16* hnx = hb + ((t & 1) ? 0 : 65536);
      st2_sc(hnx + (b << 9) + jg, nh);
      st2_sc(hnx + 32768 + (b << 9) + jg, f2bf(hnew - bf2f(nh)));
      ehs[(size_t)((b << 8) + t) * 512 + jg] = nh;
    }
    if (t < TS_ - 1)
      block_arrive(bars, ENC_G, grp, ENC_T, ENC_F, 4u, (unsigned)(t + 1));
  }
}

// ---------------- persistent decoder: 128 rec + 256 attn (4-way cset) = 384 blocks ----------------
__global__ __launch_bounds__(256, 2) void k_decoder(
    const float* __restrict__ gxd, const float* __restrict__ Wh,
    const u16* __restrict__ att, const u16* __restrict__ e2,
    u16* hb, float* pnum, float* pden, u16* __restrict__ outs, unsigned* bars)
{
  __shared__ char smem[32768];
  __shared__ float rec_s[3][16][16];
  __shared__ float hsumf[512];
  __shared__ float ps[64][4];
  __shared__ float es[64];
  __shared__ unsigned sdead;
  const int tid = threadIdx.x, bid = blockIdx.x;
  const int ln = tid & 63, wv = tid >> 6;
  const int lm = ln & 15, lq = ln >> 4, lq8 = lq << 3;
  const bool isrec = (bid < 128);
  const int set = bid >> 5, colblk = bid & 31;
  const int s16 = set << 4;
  const int jx = tid & 15, bl = tid >> 4;
  const int jg = (colblk << 4) + jx;
  const int b  = s16 + bl;
  const int ab = bid - 128, batt = ab >> 2, cset = ab & 3;
  if (tid == 0) sdead = 0;
  __syncthreads();

  short8v wfh[16], wfl[16];
  if (isrec && wv < 3) {
    const int col = (wv << 9) + (colblk << 4) + lm;
    #pragma unroll
    for (int kt = 0; kt < 16; ++kt) {
      short8v a, b2;
      #pragma unroll
      for (int i = 0; i < 8; ++i) {
        float w = Wh[(size_t)((kt << 5) + lq8 + i) * G3_ + col];
        u16 hb2 = f2bf(w);
        a[i]  = (short)hb2;
        b2[i] = (short)f2bf(w - bf2f(hb2));
      }
      wfh[kt] = a; wfl[kt] = b2;
    }
  }
  const float4v zf = {0.f, 0.f, 0.f, 0.f};
  for (int t = 0; t < TD_; ++t) {
    const u16* cur = hb + ((t & 1) ? 65536 : 0);
    if (isrec) {
      if (t) wait_flag(bars, DH_F, (unsigned)t, &sdead);
      {  // stage h(t) slice -> LDS
        short8v v[8];
        #pragma unroll
        for (int i = 0; i < 8; ++i) {
          int c = tid + (i << 8);
          int half = c >> 10, rem = c & 1023;
          int r = rem >> 6, col16 = rem & 63;
          const u16* p = cur + (half << 15) + ((s16 + r) << 9) + (col16 << 3);
          asm volatile("global_load_dwordx4 %0, %1, off sc0 sc1" : "=v"(v[i]) : "v"(p));
        }
        asm volatile("s_waitcnt vmcnt(0)" ::: "memory");
        __builtin_amdgcn_sched_barrier(0);
        #pragma unroll
        for (int i = 0; i < 8; ++i) {
          int c = tid + (i << 8);
          int half = c >> 10, rem = c & 1023;
          int r = rem >> 6, col16 = rem & 63;
          *(short8v*)(smem + ((half << 14) | (r << 10) | ((col16 << 4) ^ ((r & 7) << 4)))) = v[i];
        }
        __syncthreads();
      }
      float gzv, grv, ghv;
      {
        size_t rg = (size_t)((b << 6) + t) * G3_ + jg;
        gzv = gxd[rg]; grv = gxd[rg + 512]; ghv = gxd[rg + 1024];
      }
      int hoff = (bl << 10) | ((jg << 1) ^ ((bl & 7) << 4));
      float hold = bf2f(*(const u16*)(smem + hoff)) + bf2f(*(const u16*)(smem + 16384 + hoff));
      if (wv < 3) {
        float4v acc = zf;
        #pragma unroll
        for (int kt = 0; kt < 16; ++kt) {
          int aoff = (lm << 10) | (((kt << 6) + (lq << 4)) ^ ((lm & 7) << 4));
          short8v ah = *(const short8v*)(smem + aoff);
          short8v al = *(const short8v*)(smem + 16384 + aoff);
          acc = mfma16(ah, wfh[kt], acc);
          acc = mfma16(al, wfh[kt], acc);
          acc = mfma16(ah, wfl[kt], acc);
        }
        #pragma unroll
        for (int i = 0; i < 4; ++i) rec_s[wv][(lq << 2) + i][lm] = acc[i];
      }
      __syncthreads();
      wait_flag(bars, DP_F, (unsigned)(t + 1), &sdead);
      {  // gates: batched sc loads of 12 pnum + 4 pden partials (r10-verified order)
        const float* p0 = pnum + (size_t)(b << 2) * G3_ + jg;
        float q0,q1,q2,q3, r0,r1,r2,r3, h0,h1,h2,h3, d0,d1,d2,d3;
        asm volatile("global_load_dword %0, %1, off sc0 sc1" : "=v"(q0) : "v"(p0));
        asm volatile("global_load_dword %0, %1, off sc0 sc1" : "=v"(q1) : "v"(p0 + G3_));
        asm volatile("global_load_dword %0, %1, off sc0 sc1" : "=v"(q2) : "v"(p0 + 2*G3_));
        asm volatile("global_load_dword %0, %1, off sc0 sc1" : "=v"(q3) : "v"(p0 + 3*G3_));
        asm volatile("global_load_dword %0, %1, off sc0 sc1" : "=v"(r0) : "v"(p0 + 512));
        asm volatile("global_load_dword %0, %1, off sc0 sc1" : "=v"(r1) : "v"(p0 + G3_ + 512));
        asm volatile("global_load_dword %0, %1, off sc0 sc1" : "=v"(r2) : "v"(p0 + 2*G3_ + 512));
        asm volatile("global_load_dword %0, %1, off sc0 sc1" : "=v"(r3) : "v"(p0 + 3*G3_ + 512));
        asm volatile("global_load_dword %0, %1, off sc0 sc1" : "=v"(h0) : "v"(p0 + 1024));
        asm volatile("global_load_dword %0, %1, off sc0 sc1" : "=v"(h1) : "v"(p0 + G3_ + 1024));
        asm volatile("global_load_dword %0, %1, off sc0 sc1" : "=v"(h2) : "v"(p0 + 2*G3_ + 1024));
        asm volatile("global_load_dword %0, %1, off sc0 sc1" : "=v"(h3) : "v"(p0 + 3*G3_ + 1024));
        asm volatile("global_load_dword %0, %1, off sc0 sc1" : "=v"(d0) : "v"(pden + (b << 2)));
        asm volatile("global_load_dword %0, %1, off sc0 sc1" : "=v"(d1) : "v"(pden + (b << 2) + 1));
        asm volatile("global_load_dword %0, %1, off sc0 sc1" : "=v"(d2) : "v"(pden + (b << 2) + 2));
        asm volatile("global_load_dword %0, %1, off sc0 sc1" : "=v"(d3) : "v"(pden + (b << 2) + 3));
        asm volatile("s_waitcnt vmcnt(0)" ::: "memory");
        __builtin_amdgcn_sched_barrier(0);
        float inv = 1.f / (((d0 + d1) + d2) + d3);
        float pz  = ((q0 + q1) + q2) + q3;
        float pr  = ((r0 + r1) + r2) + r3;
        float phh = ((h0 + h1) + h2) + h3;
        float z  = sigm(gzv + pz * inv + rec_s[0][bl][jx]);
        float rr = sigm(grv + pr * inv + rec_s[1][bl][jx]);
        float hh = tanhf(ghv + phh * inv + rr * rec_s[2][bl][jx]);
        float hnew = z * hold + (1.f - z) * hh;
        u16 nh = f2bf(hnew);
        outs[(size_t)((b << 6) + t) * 512 + jg] = nh;
        if (t < TD_ - 1) {
          u16* hnx = hb + ((t & 1) ? 0 : 65536);
          st2_sc(hnx + (b << 9) + jg, nh);
          st2_sc(hnx + 32768 + (b << 9) + jg, f2bf(hnew - bf2f(nh)));
        }
      }
      if (t < TD_ - 1)
        block_arrive(bars, DH_G, set, DH_T, DH_F, 4u, (unsigned)(t + 1));
    } else {
      if (t) wait_flag(bars, DH_F, (unsigned)t, &sdead);
      if (tid < 64) {  // stage h[batt] (hi+lo summed f32)
        short8v hv = ld16_sc(cur + (batt << 9) + (tid << 3));
        short8v lv = ld16_sc(cur + 32768 + (batt << 9) + (tid << 3));
        #pragma unroll
        for (int j = 0; j < 8; ++j)
          hsumf[(tid << 3) + j] = bf2f((u16)hv[j]) + bf2f((u16)lv[j]);
      }
      __syncthreads();
      {  // scores: 64 rows, 4-way k-split over attb
        int tt = tid >> 2, kq = tid & 3;
        const u16* ep = att + (size_t)((batt << 8) + (cset << 6) + tt) * 512 + (kq << 7);
        float s = 0.f;
        #pragma unroll 4
        for (int k8 = 0; k8 < 16; ++k8) {
          short8v ev = *(const short8v*)(ep + (k8 << 3));
          #pragma unroll
          for (int j = 0; j < 8; ++j)
            s += bf2f((u16)ev[j]) * hsumf[(kq << 7) + (k8 << 3) + j];
        }
        ps[tt][kq] = s;
      }
      __syncthreads();
      if (tid < 64) {  // scores small; exp without max is safe
        float e = expf(((ps[tid][0] + ps[tid][1]) + ps[tid][2]) + ps[tid][3]);
        es[tid] = e;
        #pragma unroll
        for (int off = 32; off; off >>= 1) e += __shfl_down(e, off);
        if (tid == 0) st4_sc(&pden[ab], e);
      }
      __syncthreads();
      if (tid < 192) {  // weighted sums over e2 quarter: 8 contiguous cols/thread
        int c0 = tid << 3;
        const u16* base = e2 + (size_t)((batt << 8) + (cset << 6)) * G3_ + c0;
        float a[8] = {0.f,0.f,0.f,0.f,0.f,0.f,0.f,0.f};
        #pragma unroll 8
        for (int r = 0; r < 64; ++r) {
          short8v cv = *(const short8v*)(base + (size_t)r * G3_);
          float w = es[r];
          #pragma unroll
          for (int j = 0; j < 8; ++j)
            a[j] += w * bf2f((u16)cv[j]);
        }
        float* pn = pnum + (size_t)ab * G3_ + c0;
        float4v v0 = {a[0], a[1], a[2], a[3]};
        float4v v1 = {a[4], a[5], a[6], a[7]};
        st16f_sc(pn, v0);
        st16f_sc(pn + 4, v1);
      }
      block_arrive(bars, DP_G, ab >> 5, DP_T, DP_F, 8u, (unsigned)(t + 1));
    }
  }
}

extern "C" void kernel_launch(void* const* d_in, const int* in_sizes, int n_in,
                              void* d_out, int out_size, void* d_ws, size_t ws_size,
                              hipStream_t stream) {
  const int*   src_seq = (const int*)d_in[0];
  const int*   dec_seq = (const int*)d_in[1];
  const float* emb     = (const float*)d_in[2];
  const float* enc_Wx  = (const float*)d_in[3];
  const float* enc_Wh  = (const float*)d_in[4];
  const float* enc_b   = (const float*)d_in[5];
  const float* dec_Wx  = (const float*)d_in[6];
  const float* dec_Wh  = (const float*)d_in[7];
  const float* dec_b   = (const float*)d_in[8];
  const float* W_att   = (const float*)d_in[9];
  const float* Wd      = (const float*)d_in[10];
  const float* bd      = (const float*)d_in[11];

  // d_out doubles as scratch; final projection reads ONLY ws+inputs.
  char* ob = (char*)d_out;
  float* gx_all  = (float*)(ob + 0);           // [16384][1536] f32
  float* gxd_all = (float*)(ob + 100663296);   // [4096][1536] f32
  u16* srcE_h = (u16*)(ob + 125829120);
  u16* srcE_l = (u16*)(ob + 142606336);
  u16* decE_h = (u16*)(ob + 159383552);
  u16* decE_l = (u16*)(ob + 163577856);
  u16* ehs    = (u16*)(ob + 167772160);        // [64][256][512] bf16
  u16* attb   = (u16*)(ob + 184549376);        // E~ bf16 [16384][512]
  u16* e2b    = (u16*)(ob + 201326592);        // E~2 bf16 [16384][1536]
  u16* wxT_h  = (u16*)(ob + 251658240);
  u16* wxT_l  = (u16*)(ob + 253231104);
  u16* wdxT_h = (u16*)(ob + 254803968);
  u16* wdxT_l = (u16*)(ob + 256376832);
  u16* wxcT   = (u16*)(ob + 257949696);        // dec_Wx[512:]^T
  u16* watt   = (u16*)(ob + 259522560);        // W_att bf16 row-major
  u16* hbuf   = (u16*)(ob + 260046848);        // h dbl-buffer hi/lo
  float* pnum = (float*)(ob + 264000000);      // [256][1536] f32 (proven region, r10)
  float* pden = (float*)(ob + 266000000);      // [256]

  char* wb = (char*)d_ws;
  u16* outs      = (u16*)(wb + 0);             // [4096][512] bf16
  unsigned* bars = (unsigned*)(wb + 4194304);  // counters+flags (ws usage 4.2MB, proven)
  (void)in_sizes; (void)n_in; (void)out_size; (void)ws_size;

  hipMemsetAsync(bars, 0, 4096, stream);

  k_embed<<<4096, 256, 0, stream>>>(src_seq, emb, srcE_h, srcE_l, B_*TS_*64);
  k_embed<<<1024, 256, 0, stream>>>(dec_seq, emb, decE_h, decE_l, B_*TD_*64);
  k_transp<true ><<<dim3(24, 8), 256, 0, stream>>>(enc_Wx, G3_, wxT_h,  wxT_l,  512, G3_);
  k_transp<true ><<<dim3(24, 8), 256, 0, stream>>>(dec_Wx, G3_, wdxT_h, wdxT_l, 512, G3_);
  k_transp<false><<<dim3(24, 8), 256, 0, stream>>>(dec_Wx + (size_t)512*G3_, G3_, wxcT, nullptr, 512, G3_);
  k_cvt<<<1024, 256, 0, stream>>>(W_att, watt, 512*512);

  // gate-feeding input transforms: split-precision 3-term bf16 GEMMs
  k_gemm<true, false, true, false><<<dim3(12, 128), 256, 0, stream>>>(
      srcE_h, srcE_l, wxT_h, wxT_l, nullptr, gx_all, nullptr, enc_b, 16384, G3_, 512);
  k_gemm<true, false, true, false><<<dim3(12, 32), 256, 0, stream>>>(
      decE_h, decE_l, wdxT_h, wdxT_l, nullptr, gxd_all, nullptr, dec_b, 4096, G3_, 512);

  k_encoder<<<128, 256, 0, stream>>>(gx_all, enc_Wh, hbuf, ehs, bars);

  // attention precomputes (verified): E~ = ehs@W_att^T, E~2 = ehs@dec_Wx_ctx^T
  k_gemm<false, false, false, true><<<dim3(4, 128), 256, 0, stream>>>(
      ehs, nullptr, watt, nullptr, nullptr, nullptr, attb, nullptr, 16384, 512, 512);
  k_gemm<false, false, false, true><<<dim3(12, 128), 256, 0, stream>>>(
      ehs, nullptr, wxcT, nullptr, nullptr, nullptr, e2b, nullptr, 16384, G3_, 512);

  k_decoder<<<384, 256, 0, stream>>>(gxd_all, dec_Wh, attb, e2b,
                                     hbuf, pnum, pden, outs, bars);

  // vocab projection: A = outs (ws), B = Wd f32 on-the-fly, writes all of d_out
  k_gemm<false, true, true, false><<<dim3(250, 32), 256, 0, stream>>>(
      outs, nullptr, nullptr, nullptr, Wd, (float*)d_out, nullptr, bd, 4096, V_, 512);
}